// Round 2
// baseline (6040.302 us; speedup 1.0000x reference)
//
#include <hip/hip_runtime.h>
#include <hip/hip_bf16.h>
#include <math.h>

#define NN 50000
#define EE 500000
#define GG 1024
#define NDIM 32
#define EDIM 16
#define HH 128
#define LL 4

#define TE1 64   // edges per block, edge_mlp
#define TE2 32   // edges per block, message

typedef unsigned short ushortT;
struct ushort4T { unsigned short x, y, z, w; };

__device__ inline float bf2f(unsigned short u) {
    union { unsigned int i; float f; } v;
    v.i = ((unsigned int)u) << 16;
    return v.f;
}
__device__ inline unsigned short f2bf(float f) {
    union { float f; unsigned int i; } v;
    v.f = f;
    unsigned int r = v.i + 0x7FFFu + ((v.i >> 16) & 1u);  // RNE
    return (unsigned short)(r >> 16);
}

// h[i][j] = sum_k x[i][k]*w[k][j] + b[j]
__global__ __launch_bounds__(128) void node_embed_kernel(
        const float* __restrict__ x, const float* __restrict__ w,
        const float* __restrict__ b, float* __restrict__ h) {
    __shared__ float xs[NDIM];
    int i = blockIdx.x;
    int j = threadIdx.x;
    if (j < NDIM) xs[j] = x[i * NDIM + j];
    __syncthreads();
    float acc = b[j];
#pragma unroll
    for (int k = 0; k < NDIM; ++k) acc += xs[k] * w[k * HH + j];
    h[i * HH + j] = acc;
}

// e[i][j] = sum_k ea[i][k]*w[k][j] + b[j]  -> bf16 store
__global__ __launch_bounds__(256) void edge_embed_kernel(
        const float* __restrict__ ea, const float* __restrict__ w,
        const float* __restrict__ b, ushortT* __restrict__ e) {
    long long idx = (long long)blockIdx.x * 256 + threadIdx.x;
    if (idx >= (long long)EE * HH) return;
    int i = (int)(idx >> 7);
    int j = (int)(idx & 127);
    const float* row = ea + (size_t)i * EDIM;
    float acc = b[j];
#pragma unroll
    for (int k = 0; k < EDIM; ++k) acc += row[k] * w[k * HH + j];
    e[idx] = f2bf(acc);
}

// In-place edge MLP: e = relu(e@w1+b1)@w2+b2 for a tile of TE1 edges. e is bf16.
__global__ __launch_bounds__(256) void edge_mlp_kernel(
        ushortT* __restrict__ e,
        const float* __restrict__ w1, const float* __restrict__ b1,
        const float* __restrict__ w2, const float* __restrict__ b2) {
    __shared__ float tile[TE1][HH];   // 32 KB
    int e0 = blockIdx.x * TE1;
    int tid = threadIdx.x;
    // load TE1*HH bf16 as quads: 2048 quads / 256 threads = 8 iters
    for (int q = tid; q < TE1 * HH / 4; q += 256) {
        int r = q >> 5;            // 32 quads per row
        int c = (q & 31) * 4;
        int ed = e0 + r;
        float4 v = make_float4(0.f, 0.f, 0.f, 0.f);
        if (ed < EE) {
            ushort4T u = *reinterpret_cast<const ushort4T*>(&e[(size_t)ed * HH + c]);
            v = make_float4(bf2f(u.x), bf2f(u.y), bf2f(u.z), bf2f(u.w));
        }
        tile[r][c] = v.x; tile[r][c + 1] = v.y;
        tile[r][c + 2] = v.z; tile[r][c + 3] = v.w;
    }
    __syncthreads();

    int tcol = tid & 31, trow = tid >> 5;
    int c0 = tcol * 4, r0 = trow * 8;
    float acc[8][4];

    // phase 1: hidden = relu(tile @ w1 + b1)
#pragma unroll
    for (int i = 0; i < 8; ++i) {
        acc[i][0] = b1[c0]; acc[i][1] = b1[c0 + 1];
        acc[i][2] = b1[c0 + 2]; acc[i][3] = b1[c0 + 3];
    }
    for (int k = 0; k < HH; ++k) {
        float4 w = *reinterpret_cast<const float4*>(&w1[k * HH + c0]);
#pragma unroll
        for (int i = 0; i < 8; ++i) {
            float a = tile[r0 + i][k];
            acc[i][0] += a * w.x; acc[i][1] += a * w.y;
            acc[i][2] += a * w.z; acc[i][3] += a * w.w;
        }
    }
    __syncthreads();
#pragma unroll
    for (int i = 0; i < 8; ++i) {
        tile[r0 + i][c0]     = fmaxf(acc[i][0], 0.f);
        tile[r0 + i][c0 + 1] = fmaxf(acc[i][1], 0.f);
        tile[r0 + i][c0 + 2] = fmaxf(acc[i][2], 0.f);
        tile[r0 + i][c0 + 3] = fmaxf(acc[i][3], 0.f);
    }
    __syncthreads();

    // phase 2: out = hidden @ w2 + b2
#pragma unroll
    for (int i = 0; i < 8; ++i) {
        acc[i][0] = b2[c0]; acc[i][1] = b2[c0 + 1];
        acc[i][2] = b2[c0 + 2]; acc[i][3] = b2[c0 + 3];
    }
    for (int k = 0; k < HH; ++k) {
        float4 w = *reinterpret_cast<const float4*>(&w2[k * HH + c0]);
#pragma unroll
        for (int i = 0; i < 8; ++i) {
            float a = tile[r0 + i][k];
            acc[i][0] += a * w.x; acc[i][1] += a * w.y;
            acc[i][2] += a * w.z; acc[i][3] += a * w.w;
        }
    }
#pragma unroll
    for (int i = 0; i < 8; ++i) {
        int ed = e0 + r0 + i;
        if (ed < EE) {
            ushort4T o;
            o.x = f2bf(acc[i][0]); o.y = f2bf(acc[i][1]);
            o.z = f2bf(acc[i][2]); o.w = f2bf(acc[i][3]);
            *reinterpret_cast<ushort4T*>(&e[(size_t)ed * HH + c0]) = o;
        }
    }
}

// msg = BN(relu(concat(h[src], e) @ w1 + b1) @ w2 + b2); atomicAdd into agg[dst]
__global__ __launch_bounds__(256) void message_kernel(
        const float* __restrict__ h, const ushortT* __restrict__ e,
        const int* __restrict__ src, const int* __restrict__ dst,
        const float* __restrict__ w1, const float* __restrict__ b1,
        const float* __restrict__ w2, const float* __restrict__ b2,
        const float* __restrict__ bng, const float* __restrict__ bnb,
        float inv_std, float* __restrict__ agg) {
    __shared__ float tile[TE2][2 * HH];  // 32 KB
    __shared__ int sidx[TE2];
    int e0 = blockIdx.x * TE2;
    int tid = threadIdx.x;
    if (tid < TE2) sidx[tid] = src[e0 + tid];   // grid is exact: EE % TE2 == 0
    __syncthreads();
    // h-half: TE2*HH/4 = 1024 float4 loads
    for (int q = tid; q < TE2 * HH / 4; q += 256) {
        int r = q >> 5;
        int c = (q & 31) * 4;
        float4 v = *reinterpret_cast<const float4*>(&h[(size_t)sidx[r] * HH + c]);
        tile[r][c] = v.x; tile[r][c + 1] = v.y;
        tile[r][c + 2] = v.z; tile[r][c + 3] = v.w;
    }
    // e-half: TE2*HH/4 ushort4 loads
    for (int q = tid; q < TE2 * HH / 4; q += 256) {
        int r = q >> 5;
        int c = (q & 31) * 4;
        ushort4T u = *reinterpret_cast<const ushort4T*>(&e[(size_t)(e0 + r) * HH + c]);
        tile[r][HH + c]     = bf2f(u.x);
        tile[r][HH + c + 1] = bf2f(u.y);
        tile[r][HH + c + 2] = bf2f(u.z);
        tile[r][HH + c + 3] = bf2f(u.w);
    }
    __syncthreads();

    int tcol = tid & 31, trow = tid >> 5;
    int c0 = tcol * 4, r0 = trow * 4;
    float acc[4][4];

    // phase 1: hidden = relu(concat @ w1 + b1), K = 256
#pragma unroll
    for (int i = 0; i < 4; ++i) {
        acc[i][0] = b1[c0]; acc[i][1] = b1[c0 + 1];
        acc[i][2] = b1[c0 + 2]; acc[i][3] = b1[c0 + 3];
    }
    for (int k = 0; k < 2 * HH; ++k) {
        float4 w = *reinterpret_cast<const float4*>(&w1[k * HH + c0]);
#pragma unroll
        for (int i = 0; i < 4; ++i) {
            float a = tile[r0 + i][k];
            acc[i][0] += a * w.x; acc[i][1] += a * w.y;
            acc[i][2] += a * w.z; acc[i][3] += a * w.w;
        }
    }
    __syncthreads();
#pragma unroll
    for (int i = 0; i < 4; ++i) {
        tile[r0 + i][c0]     = fmaxf(acc[i][0], 0.f);
        tile[r0 + i][c0 + 1] = fmaxf(acc[i][1], 0.f);
        tile[r0 + i][c0 + 2] = fmaxf(acc[i][2], 0.f);
        tile[r0 + i][c0 + 3] = fmaxf(acc[i][3], 0.f);
    }
    __syncthreads();

    // phase 2: out = hidden @ w2 + b2, K = 128 (hidden lives in cols [0,128))
#pragma unroll
    for (int i = 0; i < 4; ++i) {
        acc[i][0] = b2[c0]; acc[i][1] = b2[c0 + 1];
        acc[i][2] = b2[c0 + 2]; acc[i][3] = b2[c0 + 3];
    }
    for (int k = 0; k < HH; ++k) {
        float4 w = *reinterpret_cast<const float4*>(&w2[k * HH + c0]);
#pragma unroll
        for (int i = 0; i < 4; ++i) {
            float a = tile[r0 + i][k];
            acc[i][0] += a * w.x; acc[i][1] += a * w.y;
            acc[i][2] += a * w.z; acc[i][3] += a * w.w;
        }
    }
    float g0 = bng[c0] * inv_std,     g1 = bng[c0 + 1] * inv_std;
    float g2 = bng[c0 + 2] * inv_std, g3 = bng[c0 + 3] * inv_std;
    float bb0 = bnb[c0], bb1 = bnb[c0 + 1], bb2 = bnb[c0 + 2], bb3 = bnb[c0 + 3];
#pragma unroll
    for (int i = 0; i < 4; ++i) {
        int ed = e0 + r0 + i;
        int d = dst[ed];
        atomicAdd(&agg[(size_t)d * HH + c0],     acc[i][0] * g0 + bb0);
        atomicAdd(&agg[(size_t)d * HH + c0 + 1], acc[i][1] * g1 + bb1);
        atomicAdd(&agg[(size_t)d * HH + c0 + 2], acc[i][2] * g2 + bb2);
        atomicAdd(&agg[(size_t)d * HH + c0 + 3], acc[i][3] * g3 + bb3);
    }
}

__global__ __launch_bounds__(256) void pool_kernel(
        const float* __restrict__ h, const int* __restrict__ batch,
        float* __restrict__ pooled) {
    long long idx = (long long)blockIdx.x * 256 + threadIdx.x;
    if (idx >= (long long)NN * HH) return;
    int i = (int)(idx >> 7), c = (int)(idx & 127);
    atomicAdd(&pooled[(size_t)batch[i] * HH + c], h[idx]);
}

__global__ __launch_bounds__(128) void readout_kernel(
        const float* __restrict__ pooled,
        const float* __restrict__ w1, const float* __restrict__ b1,
        const float* __restrict__ w2, const float* __restrict__ b2,
        float* __restrict__ out) {
    __shared__ float row[HH];
    __shared__ float red[HH];
    int g = blockIdx.x, j = threadIdx.x;
    row[j] = pooled[(size_t)g * HH + j];
    __syncthreads();
    float acc = b1[j];
    for (int k = 0; k < HH; ++k) acc += row[k] * w1[k * HH + j];
    red[j] = fmaxf(acc, 0.f) * w2[j];
    __syncthreads();
    for (int s = 64; s > 0; s >>= 1) {
        if (j < s) red[j] += red[j + s];
        __syncthreads();
    }
    if (j == 0) out[g] = red[0] + b2[0];
}

extern "C" void kernel_launch(void* const* d_in, const int* in_sizes, int n_in,
                              void* d_out, int out_size, void* d_ws, size_t ws_size,
                              hipStream_t stream) {
    const float* x     = (const float*)d_in[0];
    const int*   ei    = (const int*)d_in[1];
    const float* ea    = (const float*)d_in[2];
    const int*   batch = (const int*)d_in[3];
    const float* ne_w  = (const float*)d_in[4];
    const float* ne_b  = (const float*)d_in[5];
    const float* ee_w  = (const float*)d_in[6];
    const float* ee_b  = (const float*)d_in[7];
    const float* nm_w1 = (const float*)d_in[8];
    const float* nm_b1 = (const float*)d_in[9];
    const float* nm_w2 = (const float*)d_in[10];
    const float* nm_b2 = (const float*)d_in[11];
    const float* bn_g  = (const float*)d_in[12];
    const float* bn_b  = (const float*)d_in[13];
    const float* em_w1 = (const float*)d_in[14];
    const float* em_b1 = (const float*)d_in[15];
    const float* em_w2 = (const float*)d_in[16];
    const float* em_b2 = (const float*)d_in[17];
    const float* ro_w1 = (const float*)d_in[18];
    const float* ro_b1 = (const float*)d_in[19];
    const float* ro_w2 = (const float*)d_in[20];
    const float* ro_b2 = (const float*)d_in[21];

    const int* srcp = ei;
    const int* dstp = ei + EE;

    // ws layout (bytes): h0 [25.6MB] | h1 [25.6MB] | pooled [0.5MB] | ebuf bf16 [128MB]
    char* wsb = (char*)d_ws;
    float*   h0     = (float*)wsb;
    float*   h1     = h0 + (size_t)NN * HH;
    float*   pooled = h1 + (size_t)NN * HH;
    ushortT* ebuf   = (ushortT*)(pooled + (size_t)GG * HH);

    node_embed_kernel<<<NN, 128, 0, stream>>>(x, ne_w, ne_b, h0);
    {
        long long total = (long long)EE * HH;
        int nb = (int)((total + 255) / 256);
        edge_embed_kernel<<<nb, 256, 0, stream>>>(ea, ee_w, ee_b, ebuf);
    }

    const float inv_std = 1.0f / sqrtf(1.0f + 1e-5f);
    float* cur = h0;
    float* nxt = h1;
    for (int l = 0; l < LL; ++l) {
        edge_mlp_kernel<<<(EE + TE1 - 1) / TE1, 256, 0, stream>>>(
            ebuf, em_w1 + (size_t)l * HH * HH, em_b1 + l * HH,
            em_w2 + (size_t)l * HH * HH, em_b2 + l * HH);
        hipMemcpyAsync(nxt, cur, sizeof(float) * (size_t)NN * HH,
                       hipMemcpyDeviceToDevice, stream);
        message_kernel<<<EE / TE2, 256, 0, stream>>>(
            cur, ebuf, srcp, dstp,
            nm_w1 + (size_t)l * 2 * HH * HH, nm_b1 + l * HH,
            nm_w2 + (size_t)l * HH * HH, nm_b2 + l * HH,
            bn_g + l * HH, bn_b + l * HH, inv_std, nxt);
        float* t = cur; cur = nxt; nxt = t;
    }

    hipMemsetAsync(pooled, 0, sizeof(float) * (size_t)GG * HH, stream);
    {
        long long total = (long long)NN * HH;
        int nb = (int)((total + 255) / 256);
        pool_kernel<<<nb, 256, 0, stream>>>(cur, batch, pooled);
    }
    readout_kernel<<<GG, 128, 0, stream>>>(pooled, ro_w1, ro_b1, ro_w2, ro_b2,
                                           (float*)d_out);
}

// Round 3
// 1686.090 us; speedup vs baseline: 3.5824x; 3.5824x over previous
//
#include <hip/hip_runtime.h>
#include <hip/hip_bf16.h>
#include <math.h>

#define NN 50000
#define EE 500000
#define GG 1024
#define NDIM 32
#define EDIM 16
#define HH 128
#define LL 4
#define TILE 32   // edges per fused block

typedef unsigned short ushortT;
typedef __attribute__((ext_vector_type(8))) short bf16x8;   // 8 bf16 = 4 VGPR
typedef __attribute__((ext_vector_type(4))) float f32x4;    // MFMA C/D

#define MFMA16(a, b, c) __builtin_amdgcn_mfma_f32_16x16x32_bf16(a, b, c, 0, 0, 0)

__device__ inline float bf2f(ushortT u) {
    union { unsigned int i; float f; } v; v.i = ((unsigned int)u) << 16; return v.f;
}
__device__ inline ushortT f2bf(float f) {
    union { float f; unsigned int i; } v; v.f = f;
    unsigned int r = v.i + 0x7FFFu + ((v.i >> 16) & 1u);  // RNE
    return (ushortT)(r >> 16);
}
__device__ inline short f2bfs(float f) { return (short)f2bf(f); }

// Swizzled LDS A-fragment read: row-major bf16 tile, byte ^= (row&7)<<4 (T2)
__device__ inline bf16x8 lds_a(const char* base, int strideB, int row, int colByte) {
    int b = row * strideB + colByte;
    b ^= ((row & 7) << 4);
    return *reinterpret_cast<const bf16x8*>(base + b);
}

// ---------------- sort-by-dst (deterministic per call) ----------------
__global__ __launch_bounds__(256) void hist_kernel(
        const int* __restrict__ dst, int* __restrict__ counts) {
    int i = blockIdx.x * 256 + threadIdx.x;
    if (i < EE) atomicAdd(&counts[dst[i]], 1);
}

__global__ __launch_bounds__(1024) void scan_kernel(
        const int* __restrict__ counts, int* __restrict__ base) {
    __shared__ int buf[1024];
    __shared__ int carry;
    int tid = threadIdx.x;
    if (tid == 0) carry = 0;
    __syncthreads();
    for (int c0 = 0; c0 < NN; c0 += 1024) {
        int i = c0 + tid;
        int v = (i < NN) ? counts[i] : 0;
        buf[tid] = v;
        __syncthreads();
        for (int off = 1; off < 1024; off <<= 1) {
            int t = (tid >= off) ? buf[tid - off] : 0;
            __syncthreads();
            buf[tid] += t;
            __syncthreads();
        }
        if (i < NN) base[i] = carry + buf[tid] - v;   // exclusive
        __syncthreads();
        if (tid == 1023) carry += buf[1023];
        __syncthreads();
    }
}

__global__ __launch_bounds__(256) void build_perm_kernel(
        const int* __restrict__ src, const int* __restrict__ dst,
        const int* __restrict__ base, int* __restrict__ cnt,
        int* __restrict__ perm, int* __restrict__ srcS, int* __restrict__ dstS) {
    int i = blockIdx.x * 256 + threadIdx.x;
    if (i >= EE) return;
    int d = dst[i];
    int pos = base[d] + atomicAdd(&cnt[d], 1);
    perm[pos] = i;
    srcS[pos] = src[i];
    dstS[pos] = d;
}

// ---------------- weight prep: fp32 [K][N] -> bf16 [N][K], batched over L ----
__global__ __launch_bounds__(256) void transpose_kernel(
        const float* __restrict__ in, ushortT* __restrict__ out, int K, int N) {
    int per = K * N;
    int total = LL * per;
    int idx = blockIdx.x * 256 + threadIdx.x;
    if (idx >= total) return;
    int l = idx / per, rem = idx - l * per;
    int n = rem / K, k = rem - n * K;
    out[idx] = f2bf(in[(size_t)l * per + (size_t)k * N + n]);
}

// ---------------- embeds ----------------
__global__ __launch_bounds__(128) void node_embed_kernel(
        const float* __restrict__ x, const float* __restrict__ w,
        const float* __restrict__ b, float* __restrict__ h) {
    __shared__ float xs[NDIM];
    int i = blockIdx.x, j = threadIdx.x;
    if (j < NDIM) xs[j] = x[(size_t)i * NDIM + j];
    __syncthreads();
    float acc = b[j];
#pragma unroll
    for (int k = 0; k < NDIM; ++k) acc += xs[k] * w[k * HH + j];
    h[(size_t)i * HH + j] = acc;
}

// e_sorted[i] = embed(edge_attr[perm[i]]); 2 edges per 256-thread block
__global__ __launch_bounds__(256) void edge_embed_kernel(
        const float* __restrict__ ea, const int* __restrict__ perm,
        const float* __restrict__ w, const float* __restrict__ b,
        ushortT* __restrict__ e) {
    int i0 = blockIdx.x * 2;
    int sub = threadIdx.x >> 7, j = threadIdx.x & 127;
    __shared__ float row[2][EDIM];
    int ip = perm[i0 + sub];
    if (j < EDIM) row[sub][j] = ea[(size_t)ip * EDIM + j];
    __syncthreads();
    float acc = b[j];
#pragma unroll
    for (int k = 0; k < EDIM; ++k) acc += row[sub][k] * w[k * HH + j];
    e[(size_t)(i0 + sub) * HH + j] = f2bf(acc);
}

// ---------------- fused layer ----------------
// per 32-edge tile (dst-sorted): e = edgeMLP(e) [2 GEMMs]; msg = nodeMLP(concat(h[src],e))
// [2 GEMMs] + BN; segmented-reduce msg by dst; atomicAdd runs into agg.
template<int K>
__device__ inline void gemm_phase(const char* aBase, int aStride, int aColByte,
        const ushortT* __restrict__ wT, const float* __restrict__ bias,
        int wave, int l15, int lg, f32x4 acc[2][2]) {
#pragma unroll
    for (int ntl = 0; ntl < 2; ++ntl) {
        float bb = bias[(wave * 2 + ntl) * 16 + l15];
        f32x4 iv = {bb, bb, bb, bb};
        acc[0][ntl] = iv;
        acc[1][ntl] = iv;
    }
#pragma unroll
    for (int ks = 0; ks < K / 32; ++ks) {
        int kk = ks * 32 + lg * 8;
        bf16x8 a0 = lds_a(aBase, aStride, l15,      aColByte + kk * 2);
        bf16x8 a1 = lds_a(aBase, aStride, 16 + l15, aColByte + kk * 2);
#pragma unroll
        for (int ntl = 0; ntl < 2; ++ntl) {
            int n = (wave * 2 + ntl) * 16 + l15;
            bf16x8 b = *reinterpret_cast<const bf16x8*>(wT + (size_t)n * K + kk);
            acc[0][ntl] = MFMA16(a0, b, acc[0][ntl]);
            acc[1][ntl] = MFMA16(a1, b, acc[1][ntl]);
        }
    }
}

__device__ inline void write_frag_bf16(char* base, int strideB, int colByteBase,
        int wave, int l15, int lg, f32x4 acc[2][2], bool relu) {
#pragma unroll
    for (int mt = 0; mt < 2; ++mt)
#pragma unroll
        for (int ntl = 0; ntl < 2; ++ntl) {
            int col = (wave * 2 + ntl) * 16 + l15;
#pragma unroll
            for (int r = 0; r < 4; ++r) {
                int row = mt * 16 + lg * 4 + r;
                int b = row * strideB + colByteBase + col * 2;
                b ^= ((row & 7) << 4);
                float v = acc[mt][ntl][r];
                if (relu) v = fmaxf(v, 0.f);
                *reinterpret_cast<ushortT*>(base + b) = (ushortT)f2bf(v);
            }
        }
}

__global__ __launch_bounds__(256) void fused_layer_kernel(
        const float* __restrict__ h, ushortT* __restrict__ e,
        const int* __restrict__ srcS, const int* __restrict__ dstS,
        const ushortT* __restrict__ ew1t, const float* __restrict__ eb1,
        const ushortT* __restrict__ ew2t, const float* __restrict__ eb2,
        const ushortT* __restrict__ nw1t, const float* __restrict__ nb1,
        const ushortT* __restrict__ nw2t, const float* __restrict__ nb2,
        const float* __restrict__ bng, const float* __restrict__ bnb,
        float inv_std, float* __restrict__ agg, int writeE) {
    __shared__ __align__(16) char catM[TILE * 512];   // [32][256] bf16 / later [32][128] f32
    __shared__ __align__(16) char hidM[TILE * 256];   // [32][128] bf16
    __shared__ int sidx[TILE], dstx[TILE];
    int e0 = blockIdx.x * TILE;
    int tid = threadIdx.x;
    if (tid < TILE) { sidx[tid] = srcS[e0 + tid]; dstx[tid] = dstS[e0 + tid]; }
    __syncthreads();

    // stage e -> cat cols [128,256)
    for (int c = tid; c < TILE * 16; c += 256) {          // 16 chunks of 8 bf16 per row
        int row = c >> 4, col8 = (c & 15) * 8;
        bf16x8 v = *reinterpret_cast<const bf16x8*>(e + (size_t)(e0 + row) * HH + col8);
        int b = row * 512 + 256 + col8 * 2; b ^= ((row & 7) << 4);
        *reinterpret_cast<bf16x8*>(catM + b) = v;
    }
    // stage h[src] -> cat cols [0,128) (f32 -> bf16)
    for (int c = tid; c < TILE * 16; c += 256) {
        int row = c >> 4, col8 = (c & 15) * 8;
        const float* hp = h + (size_t)sidx[row] * HH + col8;
        float4 va = *reinterpret_cast<const float4*>(hp);
        float4 vb = *reinterpret_cast<const float4*>(hp + 4);
        bf16x8 o;
        o[0] = f2bfs(va.x); o[1] = f2bfs(va.y); o[2] = f2bfs(va.z); o[3] = f2bfs(va.w);
        o[4] = f2bfs(vb.x); o[5] = f2bfs(vb.y); o[6] = f2bfs(vb.z); o[7] = f2bfs(vb.w);
        int b = row * 512 + col8 * 2; b ^= ((row & 7) << 4);
        *reinterpret_cast<bf16x8*>(catM + b) = o;
    }
    __syncthreads();

    int wave = tid >> 6, lane = tid & 63, l15 = lane & 15, lg = lane >> 4;
    f32x4 acc[2][2];

    // edge MLP phase 1: hid = relu(e @ ew1 + eb1), K=128 (A = cat cols 128..)
    gemm_phase<HH>(catM, 512, 256, ew1t, eb1, wave, l15, lg, acc);
    write_frag_bf16(hidM, 256, 0, wave, l15, lg, acc, true);
    __syncthreads();

    // edge MLP phase 2: e_new = hid @ ew2 + eb2 -> cat cols 128..
    gemm_phase<HH>(hidM, 256, 0, ew2t, eb2, wave, l15, lg, acc);
    write_frag_bf16(catM, 512, 256, wave, l15, lg, acc, false);
    __syncthreads();

    // copy e_new out (coalesced), except on the last layer
    if (writeE) {
        for (int c = tid; c < TILE * 16; c += 256) {
            int row = c >> 4, col8 = (c & 15) * 8;
            int b = row * 512 + 256 + col8 * 2; b ^= ((row & 7) << 4);
            bf16x8 v = *reinterpret_cast<const bf16x8*>(catM + b);
            *reinterpret_cast<bf16x8*>(e + (size_t)(e0 + row) * HH + col8) = v;
        }
    }

    // message phase 1: hid = relu(cat @ nw1 + nb1), K=256
    gemm_phase<2 * HH>(catM, 512, 0, nw1t, nb1, wave, l15, lg, acc);
    __syncthreads();              // cover: p2's hid reads done; also e copy-out reads done
    write_frag_bf16(hidM, 256, 0, wave, l15, lg, acc, true);
    __syncthreads();

    // message phase 2: msg = hid @ nw2 + nb2, BN, store f32 into catM [32][128]
    gemm_phase<HH>(hidM, 256, 0, nw2t, nb2, wave, l15, lg, acc);
    float* msg = reinterpret_cast<float*>(catM);
#pragma unroll
    for (int ntl = 0; ntl < 2; ++ntl) {
        int col = (wave * 2 + ntl) * 16 + l15;
        float g = bng[col] * inv_std;
        float bb = bnb[col];
#pragma unroll
        for (int mt = 0; mt < 2; ++mt)
#pragma unroll
            for (int r = 0; r < 4; ++r) {
                int row = mt * 16 + lg * 4 + r;
                msg[row * HH + col] = acc[mt][ntl][r] * g + bb;
            }
    }
    __syncthreads();

    // segmented reduction over sorted dst: one atomic per (half-tile, run, col)
    int colT = tid & 127, half = tid >> 7;
    int rbeg = half * 16, rend = rbeg + 16;
    float sum = 0.f;
    int dprev = dstx[rbeg];
    for (int r = rbeg; r < rend; ++r) {
        int d = dstx[r];
        float v = msg[r * HH + colT];
        if (d != dprev) {
            atomicAdd(&agg[(size_t)dprev * HH + colT], sum);
            sum = 0.f;
            dprev = d;
        }
        sum += v;
    }
    atomicAdd(&agg[(size_t)dprev * HH + colT], sum);
}

// ---------------- pool + readout ----------------
__global__ __launch_bounds__(256) void pool_kernel(
        const float* __restrict__ h, const int* __restrict__ batch,
        float* __restrict__ pooled) {
    long long idx = (long long)blockIdx.x * 256 + threadIdx.x;
    if (idx >= (long long)NN * HH) return;
    int i = (int)(idx >> 7), c = (int)(idx & 127);
    atomicAdd(&pooled[(size_t)batch[i] * HH + c], h[idx]);
}

__global__ __launch_bounds__(128) void readout_kernel(
        const float* __restrict__ pooled,
        const float* __restrict__ w1, const float* __restrict__ b1,
        const float* __restrict__ w2, const float* __restrict__ b2,
        float* __restrict__ out) {
    __shared__ float row[HH];
    __shared__ float red[HH];
    int g = blockIdx.x, j = threadIdx.x;
    row[j] = pooled[(size_t)g * HH + j];
    __syncthreads();
    float acc = b1[j];
    for (int k = 0; k < HH; ++k) acc += row[k] * w1[k * HH + j];
    red[j] = fmaxf(acc, 0.f) * w2[j];
    __syncthreads();
    for (int s = 64; s > 0; s >>= 1) {
        if (j < s) red[j] += red[j + s];
        __syncthreads();
    }
    if (j == 0) out[g] = red[0] + b2[0];
}

extern "C" void kernel_launch(void* const* d_in, const int* in_sizes, int n_in,
                              void* d_out, int out_size, void* d_ws, size_t ws_size,
                              hipStream_t stream) {
    const float* x     = (const float*)d_in[0];
    const int*   ei    = (const int*)d_in[1];
    const float* ea    = (const float*)d_in[2];
    const int*   batch = (const int*)d_in[3];
    const float* ne_w  = (const float*)d_in[4];
    const float* ne_b  = (const float*)d_in[5];
    const float* ee_w  = (const float*)d_in[6];
    const float* ee_b  = (const float*)d_in[7];
    const float* nm_w1 = (const float*)d_in[8];
    const float* nm_b1 = (const float*)d_in[9];
    const float* nm_w2 = (const float*)d_in[10];
    const float* nm_b2 = (const float*)d_in[11];
    const float* bn_g  = (const float*)d_in[12];
    const float* bn_b  = (const float*)d_in[13];
    const float* em_w1 = (const float*)d_in[14];
    const float* em_b1 = (const float*)d_in[15];
    const float* em_w2 = (const float*)d_in[16];
    const float* em_b2 = (const float*)d_in[17];
    const float* ro_w1 = (const float*)d_in[18];
    const float* ro_b1 = (const float*)d_in[19];
    const float* ro_w2 = (const float*)d_in[20];
    const float* ro_b2 = (const float*)d_in[21];

    const int* srcp = ei;
    const int* dstp = ei + EE;

    // workspace carve (all 16B aligned)
    char* p = (char*)d_ws;
    float* h0 = (float*)p;       p += (size_t)NN * HH * 4;
    float* h1 = (float*)p;       p += (size_t)NN * HH * 4;
    float* pooled = (float*)p;   p += (size_t)GG * HH * 4;
    ushortT* ebuf = (ushortT*)p; p += (size_t)EE * HH * 2;
    ushortT* ew1t = (ushortT*)p; p += (size_t)LL * HH * HH * 2;
    ushortT* ew2t = (ushortT*)p; p += (size_t)LL * HH * HH * 2;
    ushortT* nw1t = (ushortT*)p; p += (size_t)LL * 2 * HH * HH * 2;
    ushortT* nw2t = (ushortT*)p; p += (size_t)LL * HH * HH * 2;
    int* perm   = (int*)p;       p += (size_t)EE * 4;
    int* srcS   = (int*)p;       p += (size_t)EE * 4;
    int* dstS   = (int*)p;       p += (size_t)EE * 4;
    int* counts = (int*)p;       p += (size_t)NN * 4;
    int* basep  = (int*)p;       p += (size_t)NN * 4;
    int* cnt    = (int*)p;       p += (size_t)NN * 4;

    // ---- sort edges by dst (deterministic recompute each call) ----
    hipMemsetAsync(counts, 0, (size_t)NN * 4, stream);
    hipMemsetAsync(cnt, 0, (size_t)NN * 4, stream);
    hist_kernel<<<(EE + 255) / 256, 256, 0, stream>>>(dstp, counts);
    scan_kernel<<<1, 1024, 0, stream>>>(counts, basep);
    build_perm_kernel<<<(EE + 255) / 256, 256, 0, stream>>>(
        srcp, dstp, basep, cnt, perm, srcS, dstS);

    // ---- weight prep ----
    transpose_kernel<<<(LL * HH * HH + 255) / 256, 256, 0, stream>>>(em_w1, ew1t, HH, HH);
    transpose_kernel<<<(LL * HH * HH + 255) / 256, 256, 0, stream>>>(em_w2, ew2t, HH, HH);
    transpose_kernel<<<(LL * 2 * HH * HH + 255) / 256, 256, 0, stream>>>(nm_w1, nw1t, 2 * HH, HH);
    transpose_kernel<<<(LL * HH * HH + 255) / 256, 256, 0, stream>>>(nm_w2, nw2t, HH, HH);

    // ---- embeds ----
    node_embed_kernel<<<NN, 128, 0, stream>>>(x, ne_w, ne_b, h0);
    edge_embed_kernel<<<EE / 2, 256, 0, stream>>>(ea, perm, ee_w, ee_b, ebuf);

    // ---- layers ----
    const float inv_std = 1.0f / sqrtf(1.0f + 1e-5f);
    float* cur = h0;
    float* nxt = h1;
    for (int l = 0; l < LL; ++l) {
        hipMemcpyAsync(nxt, cur, sizeof(float) * (size_t)NN * HH,
                       hipMemcpyDeviceToDevice, stream);
        fused_layer_kernel<<<EE / TILE, 256, 0, stream>>>(
            cur, ebuf, srcS, dstS,
            ew1t + (size_t)l * HH * HH, em_b1 + l * HH,
            ew2t + (size_t)l * HH * HH, em_b2 + l * HH,
            nw1t + (size_t)l * 2 * HH * HH, nm_b1 + l * HH,
            nw2t + (size_t)l * HH * HH, nm_b2 + l * HH,
            bn_g + l * HH, bn_b + l * HH, inv_std, nxt,
            (l < LL - 1) ? 1 : 0);
        float* t = cur; cur = nxt; nxt = t;
    }

    // ---- pool + readout ----
    hipMemsetAsync(pooled, 0, sizeof(float) * (size_t)GG * HH, stream);
    {
        long long total = (long long)NN * HH;
        pool_kernel<<<(int)((total + 255) / 256), 256, 0, stream>>>(cur, batch, pooled);
    }
    readout_kernel<<<GG, 128, 0, stream>>>(pooled, ro_w1, ro_b1, ro_w2, ro_b2,
                                           (float*)d_out);
}